// Round 10
// baseline (6460.302 us; speedup 1.0000x reference)
//
#include <hip/hip_runtime.h>
#include <cstdint>
#include <cstddef>
#include <math.h>

#define NNODE 8192
#define CINP 64
#define CC 128
#define MM 4096
#define KPOS 16
#define KLARGE 127
#define KDOWN 16
#define EG (MM*KDOWN)      /* 65536 gumbel edges */
#define ETOT (EG*2)        /* 131072 total edges */
#define NEDGE 131072       /* input edge_index count */

// ---------------- threefry2x32 (exact JAX algorithm) ----------------
__host__ __device__ static inline void tf_block(uint32_t k0, uint32_t k1,
                                                uint32_t c0, uint32_t c1,
                                                uint32_t& o0, uint32_t& o1) {
  uint32_t ks2 = k0 ^ k1 ^ 0x1BD11BDAu;
  uint32_t x0 = c0 + k0, x1 = c1 + k1;
#define TFR(r) { x0 += x1; x1 = (x1 << (r)) | (x1 >> (32 - (r))); x1 ^= x0; }
  TFR(13) TFR(15) TFR(26) TFR(6)
  x0 += k1;  x1 += ks2 + 1u;
  TFR(17) TFR(29) TFR(16) TFR(24)
  x0 += ks2; x1 += k0 + 2u;
  TFR(13) TFR(15) TFR(26) TFR(6)
  x0 += k0;  x1 += k1 + 3u;
  TFR(17) TFR(29) TFR(16) TFR(24)
  x0 += k1;  x1 += ks2 + 4u;
  TFR(13) TFR(15) TFR(26) TFR(6)
  x0 += ks2; x1 += k0 + 5u;
#undef TFR
  o0 = x0; o1 = x1;
}

// partitionable random_bits (32-bit): element i <- bits1 ^ bits2 of threefry(key,(0,i))
__global__ void k_uniform(float* __restrict__ u, int n, uint32_t ka, uint32_t kb) {
  int i = blockIdx.x * 256 + threadIdx.x;
  if (i >= n) return;
  uint32_t o0, o1;
  tf_block(ka, kb, 0u, (uint32_t)i, o0, o1);
  uint32_t bits = o0 ^ o1;
  u[i] = __uint_as_float((bits >> 9) | 0x3f800000u) - 1.0f;
}

// ---------------- fp32 GEMM (value-only paths) ----------------
__global__ __launch_bounds__(256) void k_gemm32(const float* __restrict__ A, const float* __restrict__ B,
                                                const float* __restrict__ bias, float* __restrict__ Cmat, int rows) {
  int id = blockIdx.x * 256 + threadIdx.x;
  int r = id >> 7, c = id & (CC - 1);
  if (r >= rows) return;
  const float* a = A + r * CC;
  float acc = 0.f;
#pragma unroll 8
  for (int k = 0; k < CC; k++) acc = __fmaf_rn(a[k], B[k * CC + c], acc);
  if (bias) acc = __fadd_rn(acc, bias[c]);
  Cmat[id] = acc;
}

// ---------------- fp64-accumulated GEMM (selection-feeding paths) ----------------
template<int K>
__global__ __launch_bounds__(256) void k_gemm64(const float* __restrict__ A, const float* __restrict__ B,
                                                const float* __restrict__ bias, float* __restrict__ Cmat, int rows) {
  int id = blockIdx.x * 256 + threadIdx.x;
  int r = id >> 7, c = id & (CC - 1);
  if (r >= rows) return;
  const float* a = A + r * K;
  double acc = 0.0;
#pragma unroll 4
  for (int k = 0; k < K; k++) acc += (double)a[k] * (double)B[k * CC + c];
  float v = (float)acc;
  if (bias) v = __fadd_rn(v, bias[c]);
  Cmat[id] = v;
}

__global__ __launch_bounds__(256) void k_gemm_res(const float* __restrict__ A, const float* __restrict__ B,
                                                  const float* __restrict__ bias, const float* __restrict__ res,
                                                  float* __restrict__ Cmat, int rows) {
  int id = blockIdx.x * 256 + threadIdx.x;
  int r = id >> 7, c = id & (CC - 1);
  if (r >= rows) return;
  const float* a = A + r * CC;
  float acc = 0.f;
#pragma unroll 8
  for (int k = 0; k < CC; k++) acc = __fmaf_rn(a[k], B[k * CC + c], acc);
  acc = __fadd_rn(acc, bias[c]);
  Cmat[id] = __fadd_rn(acc, res[id]);
}

// ---------------- parallel fp64 column stats (fixed-order combine) ----------------
__global__ __launch_bounds__(128) void k_colsum_part(const float* __restrict__ A, int rows, int rpb,
                                                     double* __restrict__ part) {
  int c = threadIdx.x, b = blockIdx.x;
  int r0 = b * rpb, r1 = r0 + rpb; if (r1 > rows) r1 = rows;
  double s = 0.0;
  for (int r = r0; r < r1; r++) s += (double)A[(size_t)r * CC + c];
  part[(size_t)b * CC + c] = s;
}
__global__ __launch_bounds__(128) void k_colmean(const double* __restrict__ part, int np, double rows,
                                                 float* __restrict__ mean) {
  int c = threadIdx.x;
  double s = 0.0;
  for (int b = 0; b < np; b++) s += part[(size_t)b * CC + c];
  mean[c] = (float)(s / rows);
}
__global__ __launch_bounds__(128) void k_colvar_part(const float* __restrict__ A, int rows, int rpb,
                                                     const float* __restrict__ mean, double* __restrict__ part) {
  int c = threadIdx.x, b = blockIdx.x;
  int r0 = b * rpb, r1 = r0 + rpb; if (r1 > rows) r1 = rows;
  float m32 = mean[c];
  double q = 0.0;
  for (int r = r0; r < r1; r++) {
    float d = __fsub_rn(A[(size_t)r * CC + c], m32);
    q += (double)d * (double)d;
  }
  part[(size_t)b * CC + c] = q;
}
__global__ __launch_bounds__(128) void k_colvar_fin(const double* __restrict__ part, int np, double rows,
                                                    float* __restrict__ var) {
  int c = threadIdx.x;
  double s = 0.0;
  for (int b = 0; b < np; b++) s += part[(size_t)b * CC + c];
  var[c] = (float)(s / rows);
}

// fp64 chunked stats for BN over edges (value path)
__global__ __launch_bounds__(128) void k_colstat64(const float* __restrict__ A, int rows, int rpb,
                                                   double* __restrict__ dsum, double* __restrict__ dsq) {
  int c = threadIdx.x;
  int r0 = blockIdx.x * rpb;
  int r1 = r0 + rpb; if (r1 > rows) r1 = rows;
  double s = 0.0, q = 0.0;
  for (int r = r0; r < r1; r++) {
    float v = A[(size_t)r * CC + c];
    s += (double)v;
    q += (double)v * (double)v;
  }
  atomicAdd(&dsum[c], s);
  atomicAdd(&dsq[c], q);
}

__global__ __launch_bounds__(128) void k_finstat(const double* __restrict__ dsum, const double* __restrict__ dsq,
                                                 double rows, float* __restrict__ mean, float* __restrict__ var) {
  int c = threadIdx.x;
  double m = dsum[c] / rows;
  mean[c] = (float)m;
  var[c] = (float)(dsq[c] / rows - m * m);
}

// ---------------- BN + ReLU elementwise ----------------
__global__ void k_bnrelu(const float* __restrict__ in, const float* __restrict__ mean, const float* __restrict__ var,
                         const float* __restrict__ g, const float* __restrict__ b,
                         float* __restrict__ o1, float* __restrict__ o2, int total) {
  int id = blockIdx.x * 256 + threadIdx.x;
  if (id >= total) return;
  int c = id & (CC - 1);
  float sd = __fsqrt_rn(__fadd_rn(var[c], 1e-5f));
  float vv = __fdiv_rn(__fsub_rn(in[id], mean[c]), sd);
  vv = fmaxf(__fadd_rn(__fmul_rn(vv, g[c]), b[c]), 0.0f);
  o1[id] = vv;
  if (o2) o2[id] = vv;
}

// ---------------- neighbor max-pool ----------------
__global__ void k_pool(const float* __restrict__ h, const int* __restrict__ ei, float* __restrict__ pooled) {
  int id = blockIdx.x * 256 + threadIdx.x;
  int e = id >> 7, c = id & (CC - 1);
  int src = ei[e], dst = ei[NEDGE + e];
  atomicMax((int*)(pooled + (size_t)dst * CC + c), __float_as_int(h[(size_t)src * CC + c]));
}

// 64-bit unsigned max with one DPP-shuffled operand (gfx9 row_shr/row_bcast sequence)
#define FPS_DPP_STEP(CTRL)                                                              \
  {                                                                                     \
    uint32_t nlo = (uint32_t)__builtin_amdgcn_update_dpp(0, (int)klo, CTRL, 0xf, 0xf, true); \
    uint32_t nhi = (uint32_t)__builtin_amdgcn_update_dpp(0, (int)khi, CTRL, 0xf, 0xf, true); \
    unsigned long long nk = ((unsigned long long)nhi << 32) | nlo;                      \
    unsigned long long ck = ((unsigned long long)khi << 32) | klo;                      \
    if (nk > ck) { klo = nlo; khi = nhi; }                                              \
  }

// ---------------- exact FPS v7: DPP reduce + owner-written (key,coords) records ----------------
// Selection-bit-identical to R4-R8: same fp32 dist formula, same (max dist, min oid) tie-break,
// exact-conservative prune. One barrier/round; single LDS window post-barrier (keys+coords).
__global__ __launch_bounds__(512) void k_fps(const float* __restrict__ pos, int* __restrict__ idx) {
  constexpr int T = 512, P = 16;
  __shared__ unsigned int keys[NNODE];                     // 32 KB: (morton18<<13)|idx
  __shared__ float ldxs[NNODE], ldys[NNODE], ldzs[NNODE];  // 96 KB pos mirror by orig idx
  __shared__ unsigned int sel[NNODE / 32];                 // 1 KB bitmap by orig idx
  __shared__ int scn[T];
  __shared__ __align__(16) unsigned long long redk[2][8];  // double-buffered per-wave winner keys
  __shared__ __align__(16) float4 redc[2][8];              // winner coords (x,y,z,0)
  int t = threadIdx.x;
  // Morton keys + pos mirror
  for (int i = t; i < NNODE; i += T) {
    float X = pos[3 * i], Y = pos[3 * i + 1], Z = pos[3 * i + 2];
    ldxs[i] = X; ldys[i] = Y; ldzs[i] = Z;
    int cx = (int)(X * 64.0f); cx = cx < 0 ? 0 : (cx > 63 ? 63 : cx);
    int cy = (int)(Y * 64.0f); cy = cy < 0 ? 0 : (cy > 63 ? 63 : cy);
    int cz = (int)(Z * 64.0f); cz = cz < 0 ? 0 : (cz > 63 ? 63 : cz);
    unsigned int code = 0;
    for (int b = 0; b < 6; b++) {
      code |= (unsigned)((cx >> b) & 1) << (3 * b + 2);
      code |= (unsigned)((cy >> b) & 1) << (3 * b + 1);
      code |= (unsigned)((cz >> b) & 1) << (3 * b);
    }
    keys[i] = (code << 13) | (unsigned)i;
  }
  for (int i = t; i < NNODE / 32; i += T) sel[i] = 0u;
  __syncthreads();
  // bitonic sort ascending
  for (int k = 2; k <= NNODE; k <<= 1) {
    for (int j = k >> 1; j > 0; j >>= 1) {
      for (int i = t; i < NNODE; i += T) {
        int l = i ^ j;
        if (l > i) {
          unsigned a = keys[i], b = keys[l];
          bool up = ((i & k) == 0);
          if ((a > b) == up) { keys[i] = b; keys[l] = a; }
        }
      }
      __syncthreads();
    }
  }
  // my 16 sorted points -> registers (from LDS mirror); bbox; inverse-id
  float px[P], py[P], pz[P], dist[P];
  int invo[P];
  float bnx = 1e30f, bxx = -1e30f, bny = 1e30f, bxy = -1e30f, bnz = 1e30f, bxz = -1e30f;
#pragma unroll
  for (int j = 0; j < P; j++) {
    int i = (int)(keys[t * P + j] & 8191u);
    invo[j] = 8191 - i;
    px[j] = ldxs[i]; py[j] = ldys[i]; pz[j] = ldzs[i];
    dist[j] = __int_as_float(0x7f800000);
    bnx = fminf(bnx, px[j]); bxx = fmaxf(bxx, px[j]);
    bny = fminf(bny, py[j]); bxy = fmaxf(bxy, py[j]);
    bnz = fminf(bnz, pz[j]); bxz = fmaxf(bxz, pz[j]);
  }
  if (t == 0) sel[0] = 1u;   // point 0 pre-selected
  float Lx = ldxs[0], Ly = ldys[0], Lz = ldzs[0];
  float f1 = __int_as_float(0x7f800000);   // lane's max dist (forces dirty in round 0)
  unsigned long long myKey = 0ull;
  float bx = 0.f, by = 0.f, bz = 0.f;      // coords of lane's best point
  int w = t >> 6;
  __syncthreads();
  for (int it = 0; it < MM - 1; it++) {
    // exact-conservative prune: skip only when provably no dist in my bucket changes
    float cx = fminf(fmaxf(Lx, bnx), bxx);
    float cy = fminf(fmaxf(Ly, bny), bxy);
    float cz = fminf(fmaxf(Lz, bnz), bxz);
    float ddx = Lx - cx, ddy = Ly - cy, ddz = Lz - cz;
    float lb = ddx * ddx + ddy * ddy + ddz * ddz;
    if (lb * 0.98f - 1e-6f < f1) {
      // pass 1: update dists, fold max (exact same fp32 formula as sequential ref)
      float nf1 = -1.f;
#pragma unroll
      for (int j = 0; j < P; j++) {
        float dx = __fsub_rn(px[j], Lx), dy = __fsub_rn(py[j], Ly), dz = __fsub_rn(pz[j], Lz);
        float d2 = __fadd_rn(__fadd_rn(__fmul_rn(dx, dx), __fmul_rn(dy, dy)), __fmul_rn(dz, dz));
        float nd = fminf(dist[j], d2);
        dist[j] = nd;
        nf1 = fmaxf(nf1, nd);
      }
      // pass 2: winner = max invo among dist==nf1 (== lexicographic (max dist, min oid))
      int wi = -1;
#pragma unroll
      for (int j = 0; j < P; j++) {
        bool better = (dist[j] == nf1) && (invo[j] > wi);
        wi = better ? invo[j] : wi;
        bx = better ? px[j] : bx;
        by = better ? py[j] : by;
        bz = better ? pz[j] : bz;
      }
      f1 = nf1;
      myKey = ((unsigned long long)__float_as_uint(nf1) << 13) | (unsigned long long)(unsigned)wi;
    }
    // DPP wave64 max-reduce of packed u64 key (result lane 63, broadcast via readlane)
    uint32_t klo = (uint32_t)myKey, khi = (uint32_t)(myKey >> 32);
    FPS_DPP_STEP(0x111)  // row_shr:1
    FPS_DPP_STEP(0x112)  // row_shr:2
    FPS_DPP_STEP(0x114)  // row_shr:4
    FPS_DPP_STEP(0x118)  // row_shr:8
    FPS_DPP_STEP(0x142)  // row_bcast:15
    FPS_DPP_STEP(0x143)  // row_bcast:31
    uint32_t wlo = (uint32_t)__builtin_amdgcn_readlane((int)klo, 63);
    uint32_t whi = (uint32_t)__builtin_amdgcn_readlane((int)khi, 63);
    unsigned long long wk = ((unsigned long long)whi << 32) | wlo;
    int p = it & 1;
    if (myKey == wk) {   // unique owning lane writes record incl. its register-held coords
      redk[p][w] = wk;
      redc[p][w] = make_float4(bx, by, bz, 0.f);
    }
    __syncthreads();
    // single LDS window: 4x b128 keys + 8x b128 coords; pure-VALU tree carrying coords
    const ulonglong2* rp = (const ulonglong2*)&redk[p][0];
    ulonglong2 r0 = rp[0], r1 = rp[1], r2 = rp[2], r3 = rp[3];
    unsigned long long ka[8] = { r0.x, r0.y, r1.x, r1.y, r2.x, r2.y, r3.x, r3.y };
    float4 ca[8];
#pragma unroll
    for (int q = 0; q < 8; q++) ca[q] = redc[p][q];
    unsigned long long g = ka[0];
    float gx = ca[0].x, gy = ca[0].y, gz = ca[0].z;
#pragma unroll
    for (int q = 1; q < 8; q++)
      if (ka[q] > g) { g = ka[q]; gx = ca[q].x; gy = ca[q].y; gz = ca[q].z; }
    Lx = gx; Ly = gy; Lz = gz;
    if (t == 0) {
      int o = 8191 - (int)(g & 8191ull);
      sel[o >> 5] |= 1u << (o & 31);
    }
  }
  __syncthreads();
  // ordered compaction by original index
  int cnt = 0;
#pragma unroll
  for (int j = 0; j < P; j++) {
    int i = t * P + j;
    cnt += (int)((sel[i >> 5] >> (i & 31)) & 1u);
  }
  scn[t] = cnt;
  __syncthreads();
  for (int off = 1; off < T; off <<= 1) {
    int v = scn[t];
    int add = (t >= off) ? scn[t - off] : 0;
    __syncthreads();
    scn[t] = v + add;
    __syncthreads();
  }
  int p = scn[t] - cnt;
#pragma unroll
  for (int j = 0; j < P; j++) {
    int i = t * P + j;
    if ((sel[i >> 5] >> (i & 31)) & 1u) idx[p++] = i;
  }
}

// ---------------- gather x1/pos1 + exact fp64 squared norms ----------------
__global__ __launch_bounds__(128) void k_gather(const float* __restrict__ pooled, const float* __restrict__ pos,
                                                const int* __restrict__ idxi, float* __restrict__ x1,
                                                float* __restrict__ x1T, float* __restrict__ pos1,
                                                double* __restrict__ sqp, double* __restrict__ sqf) {
  int m = blockIdx.x, t = threadIdx.x;
  int src = idxi[m];
  float v = pooled[(size_t)src * CC + t];
  x1[m * CC + t] = v;
  x1T[t * MM + m] = v;
  __shared__ double s2[CC];
  s2[t] = (double)v * (double)v;
  __syncthreads();
  if (t == 0) {
    double acc = 0.0;
    for (int i = 0; i < CC; i++) acc += s2[i];
    sqf[m] = acc;
    float X = pos[3 * src], Y = pos[3 * src + 1], Z = pos[3 * src + 2];
    pos1[3 * m] = X; pos1[3 * m + 1] = Y; pos1[3 * m + 2] = Z;
    sqp[m] = (double)X * X + (double)Y * Y + (double)Z * Z;
  }
}

// ---------------- pos kNN (k=16) ----------------
__global__ __launch_bounds__(128) void k_knn_pos(const float* __restrict__ pos1, const double* __restrict__ sqp,
                                                 int* __restrict__ sedge) {
  int i = blockIdx.x, t = threadIdx.x;
  __shared__ float d[MM];
  __shared__ float rv[128];
  __shared__ int ri[128];
  double xi = pos1[3 * i], yi = pos1[3 * i + 1], zi = pos1[3 * i + 2], si = sqp[i];
  for (int j = t; j < MM; j += 128) {
    double dot = xi * (double)pos1[3 * j] + yi * (double)pos1[3 * j + 1] + zi * (double)pos1[3 * j + 2];
    float dd = (float)(si + sqp[j] - 2.0 * dot);
    d[j] = (j == i) ? __int_as_float(0x7f800000) : dd;
  }
  __syncthreads();
  for (int s = 0; s < KPOS; s++) {
    float bv = __int_as_float(0x7f800000); int bi = MM;
    for (int j = t; j < MM; j += 128) {
      float v = d[j];
      if (v < bv || (v == bv && j < bi)) { bv = v; bi = j; }
    }
    rv[t] = bv; ri[t] = bi;
    __syncthreads();
    if (t == 0) {
      for (int q = 1; q < 128; q++)
        if (rv[q] < rv[0] || (rv[q] == rv[0] && ri[q] < ri[0])) { rv[0] = rv[q]; ri[0] = ri[q]; }
      sedge[EG + i * KPOS + s] = ri[0];
      d[ri[0]] = __int_as_float(0x7f800000);
    }
    __syncthreads();
  }
}

// ---------------- feature distance matrix: fp64 acc, split accumulators, clean LDS ----------------
__global__ __launch_bounds__(256) void k_dmat(const float* __restrict__ x1, const float* __restrict__ x1T,
                                              const double* __restrict__ sqf, float* __restrict__ D) {
  __shared__ float As2[16][128];   // [q][k]
  int bid = blockIdx.x;
  int i0 = (bid >> 4) << 4;
  int j0 = (bid & 15) << 8;
  int t = threadIdx.x;
  for (int u = t; u < 16 * CC; u += 256) {
    int q = u >> 7, k = u & (CC - 1);
    As2[q][k] = x1[(i0 + q) * CC + k];
  }
  __syncthreads();
  int j = j0 + t;
  double sj = sqf[j];
#pragma unroll
  for (int pass = 0; pass < 2; pass++) {
    double acc[8];
#pragma unroll
    for (int q = 0; q < 8; q++) acc[q] = 0.0;
    for (int k = 0; k < CC; k++) {
      double bv = (double)x1T[k * MM + j];
#pragma unroll
      for (int q = 0; q < 8; q++) acc[q] += (double)As2[pass * 8 + q][k] * bv;
    }
#pragma unroll
    for (int q = 0; q < 8; q++) {
      int i = i0 + pass * 8 + q;
      float d = (float)(sqf[i] + sj - 2.0 * acc[q]);
      D[(size_t)i * MM + j] = (i == j) ? __int_as_float(0x7f800000) : d;
    }
  }
}

// ---------------- top-127 selection per row ----------------
__global__ __launch_bounds__(256) void k_knn_feat(const float* __restrict__ D, int* __restrict__ nnf) {
  int tt = threadIdx.x;
  int lane = tt & 63, wid = tt >> 6;
  int i = blockIdx.x * 4 + wid;
  const float* drow = D + (size_t)i * MM;
  __shared__ float Lv[8][256];
  __shared__ int Lj[8][256];
  float lv[8]; int lj[8];
#pragma unroll
  for (int q = 0; q < 8; q++) { lv[q] = __int_as_float(0x7f800000); lj[q] = MM; }
  for (int tix = 0; tix < MM / 64; tix++) {
    int j = lane + (tix << 6);
    float v = drow[j];
    if (v < lv[7] || (v == lv[7] && j < lj[7])) {
      lv[7] = v; lj[7] = j;
#pragma unroll
      for (int q = 7; q >= 1; q--) {
        bool sw = (lv[q] < lv[q - 1]) || (lv[q] == lv[q - 1] && lj[q] < lj[q - 1]);
        if (sw) { float tv = lv[q]; lv[q] = lv[q - 1]; lv[q - 1] = tv;
                  int tj = lj[q]; lj[q] = lj[q - 1]; lj[q - 1] = tj; }
      }
    }
  }
#pragma unroll
  for (int q = 0; q < 8; q++) { Lv[q][tt] = lv[q]; Lj[q][tt] = lj[q]; }
  int hp = 0;
  for (int s = 0; s < KLARGE; s++) {
    float hv = (hp < 8) ? Lv[hp][tt] : __int_as_float(0x7f800000);
    int hj = (hp < 8) ? Lj[hp][tt] : MM;
    float bv = hv; int bj = hj;
#pragma unroll
    for (int off = 1; off < 64; off <<= 1) {
      float ov = __shfl_xor(bv, off);
      int oj = __shfl_xor(bj, off);
      if (ov < bv || (ov == bv && oj < bj)) { bv = ov; bj = oj; }
    }
    if (lane == 0) nnf[(size_t)i * KLARGE + s] = bj;
    if (bj < MM && (bj & 63) == lane) {
      hp++;
      if (hp == 8) {
        float nv[8]; int nj[8];
#pragma unroll
        for (int q = 0; q < 8; q++) { nv[q] = __int_as_float(0x7f800000); nj[q] = MM; }
        for (int tix = 0; tix < MM / 64; tix++) {
          int j = lane + (tix << 6);
          float v = drow[j];
          bool after = (v > bv) || (v == bv && j > bj);
          if (after && (v < nv[7] || (v == nv[7] && j < nj[7]))) {
            nv[7] = v; nj[7] = j;
#pragma unroll
            for (int q = 7; q >= 1; q--) {
              bool sw = (nv[q] < nv[q - 1]) || (nv[q] == nv[q - 1] && nj[q] < nj[q - 1]);
              if (sw) { float tv = nv[q]; nv[q] = nv[q - 1]; nv[q - 1] = tv;
                        int tj = nj[q]; nj[q] = nj[q - 1]; nj[q - 1] = tj; }
            }
          }
        }
#pragma unroll
        for (int q = 0; q < 8; q++) { Lv[q][tt] = nv[q]; Lj[q][tt] = nj[q]; }
        hp = 0;
      }
    }
  }
}

// ---------------- emb ----------------
__global__ __launch_bounds__(64) void k_emb(const float* __restrict__ hg, const float* __restrict__ Wg2,
                                            const float* __restrict__ bg2, const float* __restrict__ u1,
                                            float* __restrict__ emb) {
  int m = blockIdx.x, t = threadIdx.x;
  if (t >= 20) return;
  double acc = 0.0;
  for (int k = 0; k < CC; k++) acc += (double)hg[m * CC + k] * (double)Wg2[k * 20 + t];
  float v = (float)acc;
  v = __fadd_rn(v, bg2[t]);
  v = __fadd_rn(v, __fmul_rn(u1[m * 20 + t], 1e-4f));
  emb[m * 20 + t] = v;
}

// ---------------- gumbel top-16 ----------------
__global__ __launch_bounds__(128) void k_gumbel(const float* __restrict__ emb, const int* __restrict__ nnf,
                                                const float* __restrict__ u2, int* __restrict__ sedge) {
  int i = blockIdx.x, t = threadIdx.x;
  __shared__ float ei[20];
  __shared__ float sc[KLARGE];
  __shared__ int sj[KLARGE];
  if (t < 20) ei[t] = emb[i * 20 + t];
  __syncthreads();
  if (t < KLARGE) {
    int j = nnf[(size_t)i * KLARGE + t];
    double res = 0.0;
#pragma unroll
    for (int q = 0; q < 20; q++) {
      float df = __fsub_rn(ei[q], emb[j * 20 + q]);
      res += (double)df * (double)df;
    }
    float dist = (float)sqrt(res);
    float d2 = __fmul_rn(dist, dist);
    float p = expf(-d2);
    float u = u2[i * KLARGE + t];
    float inner = logf(__fadd_rn(u, 1e-20f));
    float g = -logf(__fadd_rn(-inner, 1e-20f));
    sc[t] = __fadd_rn(logf(__fadd_rn(p, 1e-20f)), g);
    sj[t] = j;
  }
  __syncthreads();
  if (t == 0) {
    for (int s = 0; s < KDOWN; s++) {
      float bv = -__int_as_float(0x7f800000); int bs = 0;
      for (int q = 0; q < KLARGE; q++)
        if (sc[q] > bv) { bv = sc[q]; bs = q; }
      sedge[i * KDOWN + s] = sj[bs];
      sc[bs] = -__int_as_float(0x7f800000);
    }
  }
}

// ---------------- precompute bp1 = bp@Wa1 + ba1 ----------------
__global__ __launch_bounds__(128) void k_bp1(const float* __restrict__ bp, const float* __restrict__ Wa1,
                                             const float* __restrict__ ba1, float* __restrict__ bp1) {
  int t = threadIdx.x;
  float acc = 0.f;
  for (int k = 0; k < CC; k++) acc = __fmaf_rn(bp[k], Wa1[k * CC + t], acc);
  bp1[t] = __fadd_rn(acc, ba1[t]);
}

// ---------------- alpha1 (folded) ----------------
__global__ __launch_bounds__(256) void k_alpha1_elw(const float* __restrict__ P, const float* __restrict__ Q,
                                                    const float* __restrict__ pos1, const int* __restrict__ sedge,
                                                    const float* __restrict__ Wp1, const float* __restrict__ bp1,
                                                    float* __restrict__ alpha) {
  int id = blockIdx.x * 256 + threadIdx.x;
  int e = id >> 7, t = id & (CC - 1);
  int tgt = (e < EG) ? (e >> 4) : ((e - EG) >> 4);
  int src = sedge[e];
  float dpx = __fsub_rn(pos1[3 * tgt], pos1[3 * src]);
  float dpy = __fsub_rn(pos1[3 * tgt + 1], pos1[3 * src + 1]);
  float dpz = __fsub_rn(pos1[3 * tgt + 2], pos1[3 * src + 2]);
  float v = P[(size_t)tgt * CC + t] - Q[(size_t)src * CC + t];
  v = __fmaf_rn(dpx, Wp1[t], v);
  v = __fmaf_rn(dpy, Wp1[CC + t], v);
  v = __fmaf_rn(dpz, Wp1[2 * CC + t], v);
  alpha[(size_t)id] = __fadd_rn(v, bp1[t]);
}

// ---------------- alpha2: tiled fp32 GEMM with fused BN+ReLU staging ----------------
__global__ __launch_bounds__(256) void k_alpha2_gemm(const float* __restrict__ alpha_in,
                                                     float* __restrict__ alpha_out,
                                                     const float* __restrict__ mean, const float* __restrict__ var,
                                                     const float* __restrict__ g, const float* __restrict__ b,
                                                     const float* __restrict__ Wa2, const float* __restrict__ ba2) {
  __shared__ float As[16][132];
  __shared__ float Bs[16][132];
  __shared__ float scl[CC], shf[CC];
  int t = threadIdx.x;
  int e0 = blockIdx.x * 128;
  if (t < CC) {
    float sd = __fsqrt_rn(__fadd_rn(var[t], 1e-5f));
    float s = __fdiv_rn(g[t], sd);
    scl[t] = s;
    shf[t] = __fsub_rn(b[t], __fmul_rn(mean[t], s));
  }
  int te = t >> 4, tc = t & 15;
  float acc[8][8];
#pragma unroll
  for (int ii = 0; ii < 8; ii++)
#pragma unroll
    for (int jj = 0; jj < 8; jj++) acc[ii][jj] = 0.f;
  for (int kc = 0; kc < CC; kc += 16) {
    __syncthreads();
    for (int u = t; u < 16 * 128; u += 256) {
      int ee = u >> 4, kk = u & 15;
      float a = alpha_in[(size_t)(e0 + ee) * CC + kc + kk];
      int k = kc + kk;
      As[kk][ee] = fmaxf(__fmaf_rn(a, scl[k], shf[k]), 0.f);
    }
    for (int u = t; u < 16 * 128; u += 256) {
      int kk = u >> 7, c = u & 127;
      Bs[kk][c] = Wa2[(kc + kk) * CC + c];
    }
    __syncthreads();
#pragma unroll
    for (int kk = 0; kk < 16; kk++) {
      float av[8], bv[8];
      *(float4*)&av[0] = *(const float4*)&As[kk][te * 8];
      *(float4*)&av[4] = *(const float4*)&As[kk][te * 8 + 4];
      *(float4*)&bv[0] = *(const float4*)&Bs[kk][tc * 8];
      *(float4*)&bv[4] = *(const float4*)&Bs[kk][tc * 8 + 4];
#pragma unroll
      for (int ii = 0; ii < 8; ii++)
#pragma unroll
        for (int jj = 0; jj < 8; jj++) acc[ii][jj] = __fmaf_rn(av[ii], bv[jj], acc[ii][jj]);
    }
  }
#pragma unroll
  for (int ii = 0; ii < 8; ii++) {
    int e = e0 + te * 8 + ii;
#pragma unroll
    for (int jj = 0; jj < 8; jj++) {
      int c = tc * 8 + jj;
      alpha_out[(size_t)e * CC + c] = __fadd_rn(acc[ii][jj], ba2[c]);
    }
  }
}

// ---------------- per-target softmax attention + aggregate ----------------
__global__ __launch_bounds__(128) void k_outagg(const float* __restrict__ alpha, const float* __restrict__ vmat,
                                                const float* __restrict__ pos1, const int* __restrict__ sedge,
                                                const float* __restrict__ Wp, const float* __restrict__ bp,
                                                float* __restrict__ outb) {
  int m = blockIdx.x, t = threadIdx.x;
  float al[32], dl[32]; int sr[32];
  float amax = -__int_as_float(0x7f800000);
  float pmx = pos1[3 * m], pmy = pos1[3 * m + 1], pmz = pos1[3 * m + 2];
  float wp0 = Wp[t], wp1 = Wp[CC + t], wp2 = Wp[2 * CC + t], bpt = bp[t];
#pragma unroll
  for (int e = 0; e < 32; e++) {
    int row = (e < 16) ? (m * 16 + e) : (EG + m * 16 + (e - 16));
    int src = sedge[row];
    sr[e] = src;
    float a = alpha[(size_t)row * CC + t];
    al[e] = a;
    amax = fmaxf(amax, a);
    float d0 = __fsub_rn(pmx, pos1[3 * src]);
    float d1 = __fsub_rn(pmy, pos1[3 * src + 1]);
    float d2 = __fsub_rn(pmz, pos1[3 * src + 2]);
    float del = __fmaf_rn(d2, wp2, __fmaf_rn(d1, wp1, __fmul_rn(d0, wp0)));
    dl[e] = __fadd_rn(del, bpt);
  }
  float s1 = 0.f, s2 = 0.f;
#pragma unroll
  for (int e = 0; e < 32; e++) {
    float ea = expf(__fsub_rn(al[e], amax));
    s1 = __fadd_rn(s1, ea);
    float val = __fadd_rn(vmat[sr[e] * CC + t], dl[e]);
    s2 = __fmaf_rn(ea, val, s2);
  }
  outb[m * CC + t] = __fdiv_rn(s2, __fadd_rn(s1, 1e-16f));
}

// =====================================================================
extern "C" void kernel_launch(void* const* d_in, const int* in_sizes, int n_in,
                              void* d_out, int out_size, void* d_ws, size_t ws_size,
                              hipStream_t stream) {
  (void)in_sizes; (void)n_in; (void)out_size; (void)ws_size;
  const float* x    = (const float*)d_in[0];
  const float* pos  = (const float*)d_in[1];
  const int*   ei   = (const int*)d_in[2];
  const float* Wd   = (const float*)d_in[3];
  const float* bd   = (const float*)d_in[4];
  const float* gd   = (const float*)d_in[5];
  const float* btd  = (const float*)d_in[6];
  const float* Wg1  = (const float*)d_in[7];
  const float* bg1  = (const float*)d_in[8];
  const float* gg   = (const float*)d_in[9];
  const float* btg  = (const float*)d_in[10];
  const float* Wg2  = (const float*)d_in[11];
  const float* bg2  = (const float*)d_in[12];
  const float* Wlin = (const float*)d_in[13];
  const float* Wsrc = (const float*)d_in[14];
  const float* Wdst = (const float*)d_in[15];
  const float* Wp   = (const float*)d_in[16];
  const float* bp   = (const float*)d_in[17];
  const float* Wa1  = (const float*)d_in[18];
  const float* ba1  = (const float*)d_in[19];
  const float* ga   = (const float*)d_in[20];
  const float* bta  = (const float*)d_in[21];
  const float* Wa2  = (const float*)d_in[22];
  const float* ba2  = (const float*)d_in[23];
  const float* Wu   = (const float*)d_in[24];
  const float* bu   = (const float*)d_in[25];
  float* out = (float*)d_out;

  char* ws = (char*)d_ws;
  double* dsum = (double*)(ws + 0);
  double* dsq  = (double*)(ws + 1024);
  float* fmean = (float*)(ws + 2048);
  float* fvar  = (float*)(ws + 2560);
  float* BIG   = (float*)(ws + 4096);      // 64MB: D matrix, then alpha1/alpha2
  size_t off = 4096 + (size_t)16777216 * 4;
  auto alloc = [&](size_t nbytes) { void* p = ws + off; off += (nbytes + 255) & ~(size_t)255; return p; };
  float* h_lin  = (float*)alloc((size_t)NNODE * CC * 4);
  float* h      = (float*)alloc((size_t)NNODE * CC * 4);
  float* pooled = (float*)alloc((size_t)NNODE * CC * 4);
  float* x1     = (float*)alloc((size_t)MM * CC * 4);
  float* x1T    = (float*)alloc((size_t)MM * CC * 4);
  float* hgl    = (float*)alloc((size_t)MM * CC * 4);
  float* hg     = (float*)alloc((size_t)MM * CC * 4);
  float* Pm     = (float*)alloc((size_t)MM * CC * 4);
  float* Qm     = (float*)alloc((size_t)MM * CC * 4);
  float* vmat   = (float*)alloc((size_t)MM * CC * 4);
  float* outb   = (float*)alloc((size_t)MM * CC * 4);
  float* pos1   = (float*)alloc((size_t)MM * 3 * 4);
  double* sqp   = (double*)alloc((size_t)MM * 8);
  double* sqf   = (double*)alloc((size_t)MM * 8);
  float* emb    = (float*)alloc((size_t)MM * 20 * 4);
  float* u1     = (float*)alloc(81920 * 4);
  float* u2     = (float*)alloc(520192 * 4);
  int* idxi     = (int*)alloc(MM * 4);
  int* nnf      = (int*)alloc((size_t)MM * KLARGE * 4);
  int* sedge    = (int*)alloc(ETOT * 4);
  double* partA = (double*)alloc(64 * CC * 8);
  double* partB = (double*)alloc(64 * CC * 8);
  float* Wdst1  = (float*)alloc(CC * CC * 4);
  float* Wsrc1  = (float*)alloc(CC * CC * 4);
  float* Wp1    = (float*)alloc(3 * CC * 4);
  float* bp1    = (float*)alloc(CC * 4);

  // threefry partitionable split: child j = outputs of tf(key,(0,j)); key(42)=(0,42)
  uint32_t o0, o1, k1a, k1b, k2a, k2b;
  tf_block(0u, 42u, 0u, 0u, o0, o1); k1a = o0; k1b = o1;
  tf_block(0u, 42u, 0u, 1u, o0, o1); k2a = o0; k2b = o1;

  // ---- downlayer ----
  k_gemm64<CINP><<<dim3(NNODE * CC / 256), dim3(256), 0, stream>>>(x, Wd, bd, h_lin, NNODE);
  k_colsum_part<<<dim3(64), dim3(128), 0, stream>>>(h_lin, NNODE, 128, partA);
  k_colmean<<<dim3(1), dim3(128), 0, stream>>>(partA, 64, (double)NNODE, fmean);
  k_colvar_part<<<dim3(64), dim3(128), 0, stream>>>(h_lin, NNODE, 128, fmean, partB);
  k_colvar_fin<<<dim3(1), dim3(128), 0, stream>>>(partB, 64, (double)NNODE, fvar);
  k_bnrelu<<<dim3(NNODE * CC / 256), dim3(256), 0, stream>>>(h_lin, fmean, fvar, gd, btd, h, pooled, NNODE * CC);
  k_pool<<<dim3(NEDGE * CC / 256), dim3(256), 0, stream>>>(h, ei, pooled);
  k_fps<<<dim3(1), dim3(512), 0, stream>>>(pos, idxi);
  k_gather<<<dim3(MM), dim3(128), 0, stream>>>(pooled, pos, idxi, x1, x1T, pos1, sqp, sqf);

  // ---- generate_graph ----
  k_knn_pos<<<dim3(MM), dim3(128), 0, stream>>>(pos1, sqp, sedge);
  k_dmat<<<dim3(4096), dim3(256), 0, stream>>>(x1, x1T, sqf, BIG);
  k_knn_feat<<<dim3(MM / 4), dim3(256), 0, stream>>>(BIG, nnf);
  k_gemm64<CC><<<dim3(MM * CC / 256), dim3(256), 0, stream>>>(x1, Wg1, bg1, hgl, MM);
  k_colsum_part<<<dim3(32), dim3(128), 0, stream>>>(hgl, MM, 128, partA);
  k_colmean<<<dim3(1), dim3(128), 0, stream>>>(partA, 32, (double)MM, fmean);
  k_colvar_part<<<dim3(32), dim3(128), 0, stream>>>(hgl, MM, 128, fmean, partB);
  k_colvar_fin<<<dim3(1), dim3(128), 0, stream>>>(partB, 32, (double)MM, fvar);
  k_bnrelu<<<dim3(MM * CC / 256), dim3(256), 0, stream>>>(hgl, fmean, fvar, gg, btg, hg, (float*)nullptr, MM * CC);
  k_uniform<<<dim3((81920 + 255) / 256), dim3(256), 0, stream>>>(u1, 81920, k1a, k1b);
  k_uniform<<<dim3((520192 + 255) / 256), dim3(256), 0, stream>>>(u2, 520192, k2a, k2b);
  k_emb<<<dim3(MM), dim3(64), 0, stream>>>(hg, Wg2, bg2, u1, emb);
  k_gumbel<<<dim3(MM), dim3(128), 0, stream>>>(emb, nnf, u2, sedge);

  // ---- PointTransformerConv (folded alpha1 + tiled alpha2) ----
  k_gemm32<<<dim3(CC * CC / 256), dim3(256), 0, stream>>>(Wdst, Wa1, (const float*)nullptr, Wdst1, CC);
  k_gemm32<<<dim3(CC * CC / 256), dim3(256), 0, stream>>>(Wsrc, Wa1, (const float*)nullptr, Wsrc1, CC);
  k_gemm32<<<dim3(2), dim3(256), 0, stream>>>(Wp, Wa1, (const float*)nullptr, Wp1, 3);
  k_bp1<<<dim3(1), dim3(128), 0, stream>>>(bp, Wa1, ba1, bp1);
  k_gemm32<<<dim3(MM * CC / 256), dim3(256), 0, stream>>>(x1, Wdst1, (const float*)nullptr, Pm, MM);
  k_gemm32<<<dim3(MM * CC / 256), dim3(256), 0, stream>>>(x1, Wsrc1, (const float*)nullptr, Qm, MM);
  k_gemm32<<<dim3(MM * CC / 256), dim3(256), 0, stream>>>(x1, Wlin, (const float*)nullptr, vmat, MM);
  k_alpha1_elw<<<dim3(ETOT * CC / 256), dim3(256), 0, stream>>>(Pm, Qm, pos1, sedge, Wp1, bp1, BIG);
  hipMemsetAsync(ws, 0, 2048, stream);
  k_colstat64<<<dim3(256), dim3(128), 0, stream>>>(BIG, ETOT, 512, dsum, dsq);
  k_finstat<<<dim3(1), dim3(128), 0, stream>>>(dsum, dsq, (double)ETOT, fmean, fvar);
  k_alpha2_gemm<<<dim3(ETOT / 128), dim3(256), 0, stream>>>(BIG, BIG, fmean, fvar, ga, bta, Wa2, ba2);
  k_outagg<<<dim3(MM), dim3(128), 0, stream>>>(BIG, vmat, pos1, sedge, Wp, bp, outb);
  k_gemm_res<<<dim3(MM * CC / 256), dim3(256), 0, stream>>>(outb, Wu, bu, x1, out, MM);
}

// Round 11
// 5030.574 us; speedup vs baseline: 1.2842x; 1.2842x over previous
//
#include <hip/hip_runtime.h>
#include <cstdint>
#include <cstddef>
#include <math.h>

#define NNODE 8192
#define CINP 64
#define CC 128
#define MM 4096
#define KPOS 16
#define KLARGE 127
#define KDOWN 16
#define EG (MM*KDOWN)      /* 65536 gumbel edges */
#define ETOT (EG*2)        /* 131072 total edges */
#define NEDGE 131072       /* input edge_index count */

// ---------------- threefry2x32 (exact JAX algorithm) ----------------
__host__ __device__ static inline void tf_block(uint32_t k0, uint32_t k1,
                                                uint32_t c0, uint32_t c1,
                                                uint32_t& o0, uint32_t& o1) {
  uint32_t ks2 = k0 ^ k1 ^ 0x1BD11BDAu;
  uint32_t x0 = c0 + k0, x1 = c1 + k1;
#define TFR(r) { x0 += x1; x1 = (x1 << (r)) | (x1 >> (32 - (r))); x1 ^= x0; }
  TFR(13) TFR(15) TFR(26) TFR(6)
  x0 += k1;  x1 += ks2 + 1u;
  TFR(17) TFR(29) TFR(16) TFR(24)
  x0 += ks2; x1 += k0 + 2u;
  TFR(13) TFR(15) TFR(26) TFR(6)
  x0 += k0;  x1 += k1 + 3u;
  TFR(17) TFR(29) TFR(16) TFR(24)
  x0 += k1;  x1 += ks2 + 4u;
  TFR(13) TFR(15) TFR(26) TFR(6)
  x0 += ks2; x1 += k0 + 5u;
#undef TFR
  o0 = x0; o1 = x1;
}

// ---------------- fp32 GEMM (value-only paths) ----------------
__global__ __launch_bounds__(256) void k_gemm32(const float* __restrict__ A, const float* __restrict__ B,
                                                const float* __restrict__ bias, float* __restrict__ Cmat, int rows) {
  int id = blockIdx.x * 256 + threadIdx.x;
  int r = id >> 7, c = id & (CC - 1);
  if (r >= rows) return;
  const float* a = A + r * CC;
  float acc = 0.f;
#pragma unroll 8
  for (int k = 0; k < CC; k++) acc = __fmaf_rn(a[k], B[k * CC + c], acc);
  if (bias) acc = __fadd_rn(acc, bias[c]);
  Cmat[id] = acc;
}

// ---------------- fp64-accumulated GEMM (selection-feeding paths) ----------------
template<int K>
__global__ __launch_bounds__(256) void k_gemm64(const float* __restrict__ A, const float* __restrict__ B,
                                                const float* __restrict__ bias, float* __restrict__ Cmat, int rows) {
  int id = blockIdx.x * 256 + threadIdx.x;
  int r = id >> 7, c = id & (CC - 1);
  if (r >= rows) return;
  const float* a = A + r * K;
  double acc = 0.0;
#pragma unroll 4
  for (int k = 0; k < K; k++) acc += (double)a[k] * (double)B[k * CC + c];
  float v = (float)acc;
  if (bias) v = __fadd_rn(v, bias[c]);
  Cmat[id] = v;
}

__global__ __launch_bounds__(256) void k_gemm_res(const float* __restrict__ A, const float* __restrict__ B,
                                                  const float* __restrict__ bias, const float* __restrict__ res,
                                                  float* __restrict__ Cmat, int rows) {
  int id = blockIdx.x * 256 + threadIdx.x;
  int r = id >> 7, c = id & (CC - 1);
  if (r >= rows) return;
  const float* a = A + r * CC;
  float acc = 0.f;
#pragma unroll 8
  for (int k = 0; k < CC; k++) acc = __fmaf_rn(a[k], B[k * CC + c], acc);
  acc = __fadd_rn(acc, bias[c]);
  Cmat[id] = __fadd_rn(acc, res[id]);
}

// ---------------- parallel fp64 column stats (fixed-order combine) ----------------
__global__ __launch_bounds__(128) void k_colsum_part(const float* __restrict__ A, int rows, int rpb,
                                                     double* __restrict__ part) {
  int c = threadIdx.x, b = blockIdx.x;
  int r0 = b * rpb, r1 = r0 + rpb; if (r1 > rows) r1 = rows;
  double s = 0.0;
  for (int r = r0; r < r1; r++) s += (double)A[(size_t)r * CC + c];
  part[(size_t)b * CC + c] = s;
}
__global__ __launch_bounds__(128) void k_colmean(const double* __restrict__ part, int np, double rows,
                                                 float* __restrict__ mean) {
  int c = threadIdx.x;
  double s = 0.0;
  for (int b = 0; b < np; b++) s += part[(size_t)b * CC + c];
  mean[c] = (float)(s / rows);
}
__global__ __launch_bounds__(128) void k_colvar_part(const float* __restrict__ A, int rows, int rpb,
                                                     const float* __restrict__ mean, double* __restrict__ part) {
  int c = threadIdx.x, b = blockIdx.x;
  int r0 = b * rpb, r1 = r0 + rpb; if (r1 > rows) r1 = rows;
  float m32 = mean[c];
  double q = 0.0;
  for (int r = r0; r < r1; r++) {
    float d = __fsub_rn(A[(size_t)r * CC + c], m32);
    q += (double)d * (double)d;
  }
  part[(size_t)b * CC + c] = q;
}
__global__ __launch_bounds__(128) void k_colvar_fin(const double* __restrict__ part, int np, double rows,
                                                    float* __restrict__ var) {
  int c = threadIdx.x;
  double s = 0.0;
  for (int b = 0; b < np; b++) s += part[(size_t)b * CC + c];
  var[c] = (float)(s / rows);
}

// fp64 chunked stats for BN over edges (value path)
__global__ __launch_bounds__(128) void k_colstat64(const float* __restrict__ A, int rows, int rpb,
                                                   double* __restrict__ dsum, double* __restrict__ dsq) {
  int c = threadIdx.x;
  int r0 = blockIdx.x * rpb;
  int r1 = r0 + rpb; if (r1 > rows) r1 = rows;
  double s = 0.0, q = 0.0;
  for (int r = r0; r < r1; r++) {
    float v = A[(size_t)r * CC + c];
    s += (double)v;
    q += (double)v * (double)v;
  }
  atomicAdd(&dsum[c], s);
  atomicAdd(&dsq[c], q);
}

__global__ __launch_bounds__(128) void k_finstat(const double* __restrict__ dsum, const double* __restrict__ dsq,
                                                 double rows, float* __restrict__ mean, float* __restrict__ var) {
  int c = threadIdx.x;
  double m = dsum[c] / rows;
  mean[c] = (float)m;
  var[c] = (float)(dsq[c] / rows - m * m);
}

// ---------------- BN + ReLU elementwise ----------------
__global__ void k_bnrelu(const float* __restrict__ in, const float* __restrict__ mean, const float* __restrict__ var,
                         const float* __restrict__ g, const float* __restrict__ b,
                         float* __restrict__ o1, float* __restrict__ o2, int total) {
  int id = blockIdx.x * 256 + threadIdx.x;
  if (id >= total) return;
  int c = id & (CC - 1);
  float sd = __fsqrt_rn(__fadd_rn(var[c], 1e-5f));
  float vv = __fdiv_rn(__fsub_rn(in[id], mean[c]), sd);
  vv = fmaxf(__fadd_rn(__fmul_rn(vv, g[c]), b[c]), 0.0f);
  o1[id] = vv;
  if (o2) o2[id] = vv;
}

// ---------------- neighbor max-pool ----------------
__global__ void k_pool(const float* __restrict__ h, const int* __restrict__ ei, float* __restrict__ pooled) {
  int id = blockIdx.x * 256 + threadIdx.x;
  int e = id >> 7, c = id & (CC - 1);
  int src = ei[e], dst = ei[NEDGE + e];
  atomicMax((int*)(pooled + (size_t)dst * CC + c), __float_as_int(h[(size_t)src * CC + c]));
}

// 64-bit unsigned max with one DPP-shuffled operand (fill=0 identity for max)
#define FPS_DPP_STEP(CTRL)                                                              \
  {                                                                                     \
    uint32_t nlo = (uint32_t)__builtin_amdgcn_update_dpp(0, (int)klo, CTRL, 0xf, 0xf, true); \
    uint32_t nhi = (uint32_t)__builtin_amdgcn_update_dpp(0, (int)khi, CTRL, 0xf, 0xf, true); \
    unsigned long long nk = ((unsigned long long)nhi << 32) | nlo;                      \
    unsigned long long ck = ((unsigned long long)khi << 32) | klo;                      \
    if (nk > ck) { klo = nlo; khi = nhi; }                                              \
  }

// 64-bit unsigned min with one DPP-shuffled operand (old=-1 identity for min)
#define KNN_DPP_MIN_STEP(CTRL)                                                          \
  {                                                                                     \
    uint32_t nlo = (uint32_t)__builtin_amdgcn_update_dpp(-1, (int)klo, CTRL, 0xf, 0xf, false); \
    uint32_t nhi = (uint32_t)__builtin_amdgcn_update_dpp(-1, (int)khi, CTRL, 0xf, 0xf, false); \
    unsigned long long nk = ((unsigned long long)nhi << 32) | nlo;                      \
    unsigned long long ck = ((unsigned long long)khi << 32) | klo;                      \
    if (nk < ck) { klo = nlo; khi = nhi; }                                              \
  }

// ---------------- k_front: block 0 = exact FPS (R8-verbatim); other blocks = input-only work ----------------
// Worker math replicated op-for-op from the standalone kernels it replaces (bit-identical).
#define FB_HL   2049        /* [1, 2049): h_lin = x@Wd+bd, fp64 acc */
#define FB_U1   2209        /* [2049, 2209): u1 uniforms */
#define FB_U2   3225        /* [2209, 3225): u2 uniforms */
#define FB_W1   3257        /* [3225, 3257): Wdst1 = Wdst@Wa1 */
#define FB_W2   3289        /* [3257, 3289): Wsrc1 = Wsrc@Wa1 */
#define FB_WP   3289        /* [3289]: Wp1 = Wp@Wa1 */
#define FB_BP   3290        /* [3290]: bp1 = bp@Wa1+ba1 */
#define FB_GRID 3291

__global__ __launch_bounds__(512) void k_front(const float* __restrict__ pos, int* __restrict__ idx,
                                               const float* __restrict__ x, const float* __restrict__ Wd,
                                               const float* __restrict__ bd, float* __restrict__ h_lin,
                                               float* __restrict__ u1, float* __restrict__ u2,
                                               uint32_t k1a, uint32_t k1b, uint32_t k2a, uint32_t k2b,
                                               const float* __restrict__ Wdst, const float* __restrict__ Wsrc,
                                               const float* __restrict__ Wa1, const float* __restrict__ Wp,
                                               const float* __restrict__ bp, const float* __restrict__ ba1,
                                               float* __restrict__ Wdst1, float* __restrict__ Wsrc1,
                                               float* __restrict__ Wp1, float* __restrict__ bp1) {
  int bid = blockIdx.x, t = threadIdx.x;
  if (bid == 0) {
    // ======== exact FPS v5 (R8 verbatim): DPP reduce + u64 records + LDS pos mirror ========
    constexpr int T = 512, P = 16;
    __shared__ unsigned int keys[NNODE];
    __shared__ float ldx[NNODE], ldy[NNODE], ldz[NNODE];
    __shared__ unsigned int sel[NNODE / 32];
    __shared__ int scn[T];
    __shared__ __align__(16) unsigned long long redk[2][8];
    for (int i = t; i < NNODE; i += T) {
      float X = pos[3 * i], Y = pos[3 * i + 1], Z = pos[3 * i + 2];
      ldx[i] = X; ldy[i] = Y; ldz[i] = Z;
      int cx = (int)(X * 64.0f); cx = cx < 0 ? 0 : (cx > 63 ? 63 : cx);
      int cy = (int)(Y * 64.0f); cy = cy < 0 ? 0 : (cy > 63 ? 63 : cy);
      int cz = (int)(Z * 64.0f); cz = cz < 0 ? 0 : (cz > 63 ? 63 : cz);
      unsigned int code = 0;
      for (int b = 0; b < 6; b++) {
        code |= (unsigned)((cx >> b) & 1) << (3 * b + 2);
        code |= (unsigned)((cy >> b) & 1) << (3 * b + 1);
        code |= (unsigned)((cz >> b) & 1) << (3 * b);
      }
      keys[i] = (code << 13) | (unsigned)i;
    }
    for (int i = t; i < NNODE / 32; i += T) sel[i] = 0u;
    __syncthreads();
    for (int k = 2; k <= NNODE; k <<= 1) {
      for (int j = k >> 1; j > 0; j >>= 1) {
        for (int i = t; i < NNODE; i += T) {
          int l = i ^ j;
          if (l > i) {
            unsigned a = keys[i], b = keys[l];
            bool up = ((i & k) == 0);
            if ((a > b) == up) { keys[i] = b; keys[l] = a; }
          }
        }
        __syncthreads();
      }
    }
    float px[P], py[P], pz[P], dist[P];
    uint32_t invo[P];
    float bnx = 1e30f, bxx = -1e30f, bny = 1e30f, bxy = -1e30f, bnz = 1e30f, bxz = -1e30f;
#pragma unroll
    for (int j = 0; j < P; j++) {
      int i = (int)(keys[t * P + j] & 8191u);
      invo[j] = (uint32_t)(8191 - i);
      px[j] = ldx[i]; py[j] = ldy[i]; pz[j] = ldz[i];
      dist[j] = __int_as_float(0x7f800000);
      bnx = fminf(bnx, px[j]); bxx = fmaxf(bxx, px[j]);
      bny = fminf(bny, py[j]); bxy = fmaxf(bxy, py[j]);
      bnz = fminf(bnz, pz[j]); bxz = fmaxf(bxz, pz[j]);
    }
    if (t == 0) sel[0] = 1u;
    float Lx = ldx[0], Ly = ldy[0], Lz = ldz[0];
    float myMax = __int_as_float(0x7f800000);
    unsigned long long myKey = 0ull;
    int w = t >> 6, lane = t & 63;
    __syncthreads();
    for (int it = 0; it < MM - 1; it++) {
      float cx = fminf(fmaxf(Lx, bnx), bxx);
      float cy = fminf(fmaxf(Ly, bny), bxy);
      float cz = fminf(fmaxf(Lz, bnz), bxz);
      float ddx = Lx - cx, ddy = Ly - cy, ddz = Lz - cz;
      float lb = ddx * ddx + ddy * ddy + ddz * ddz;
      if (lb * 0.98f - 1e-6f < myMax) {
        unsigned long long bk = 0ull;
#pragma unroll
        for (int j = 0; j < P; j++) {
          float dx = __fsub_rn(px[j], Lx), dy = __fsub_rn(py[j], Ly), dz = __fsub_rn(pz[j], Lz);
          float d2 = __fadd_rn(__fadd_rn(__fmul_rn(dx, dx), __fmul_rn(dy, dy)), __fmul_rn(dz, dz));
          float nd = fminf(dist[j], d2);
          dist[j] = nd;
          unsigned long long kj = ((unsigned long long)__float_as_uint(nd) << 13) | (unsigned long long)invo[j];
          if (kj > bk) bk = kj;
        }
        myKey = bk;
        myMax = __uint_as_float((uint32_t)(bk >> 13));
      }
      uint32_t klo = (uint32_t)myKey, khi = (uint32_t)(myKey >> 32);
      FPS_DPP_STEP(0x111)
      FPS_DPP_STEP(0x112)
      FPS_DPP_STEP(0x114)
      FPS_DPP_STEP(0x118)
      FPS_DPP_STEP(0x142)
      FPS_DPP_STEP(0x143)
      uint32_t wlo = (uint32_t)__builtin_amdgcn_readlane((int)klo, 63);
      uint32_t whi = (uint32_t)__builtin_amdgcn_readlane((int)khi, 63);
      unsigned long long wk = ((unsigned long long)whi << 32) | wlo;
      int p = it & 1;
      if (lane == 0) redk[p][w] = wk;
      __syncthreads();
      const ulonglong2* rp = (const ulonglong2*)&redk[p][0];
      ulonglong2 r0 = rp[0], r1 = rp[1], r2 = rp[2], r3 = rp[3];
      unsigned long long m0 = r0.x > r0.y ? r0.x : r0.y;
      unsigned long long m1 = r1.x > r1.y ? r1.x : r1.y;
      unsigned long long m2 = r2.x > r2.y ? r2.x : r2.y;
      unsigned long long m3 = r3.x > r3.y ? r3.x : r3.y;
      unsigned long long ga = m0 > m1 ? m0 : m1;
      unsigned long long gb = m2 > m3 ? m2 : m3;
      unsigned long long g = ga > gb ? ga : gb;
      int o = 8191 - (int)(g & 8191ull);
      Lx = ldx[o]; Ly = ldy[o]; Lz = ldz[o];
      if (t == 0) atomicOr((int*)&sel[o >> 5], (int)(1u << (o & 31)));
    }
    __syncthreads();
    int cnt = 0;
#pragma unroll
    for (int j = 0; j < P; j++) {
      int i = t * P + j;
      cnt += (int)((sel[i >> 5] >> (i & 31)) & 1u);
    }
    scn[t] = cnt;
    __syncthreads();
    for (int off = 1; off < T; off <<= 1) {
      int v = scn[t];
      int add = (t >= off) ? scn[t - off] : 0;
      __syncthreads();
      scn[t] = v + add;
      __syncthreads();
    }
    int p = scn[t] - cnt;
#pragma unroll
    for (int j = 0; j < P; j++) {
      int i = t * P + j;
      if ((sel[i >> 5] >> (i & 31)) & 1u) idx[p++] = i;
    }
    return;
  }
  if (bid < FB_HL) {         // h_lin = x@Wd + bd (fp64 acc, op-for-op as k_gemm64<64>)
    int id = (bid - 1) * 512 + t;
    int r = id >> 7, c = id & (CC - 1);
    const float* a = x + r * CINP;
    double acc = 0.0;
#pragma unroll 4
    for (int k = 0; k < CINP; k++) acc += (double)a[k] * (double)Wd[k * CC + c];
    float v = (float)acc;
    v = __fadd_rn(v, bd[c]);
    h_lin[id] = v;
    return;
  }
  if (bid < FB_U1) {         // u1 uniforms (exact k_uniform math)
    int i = (bid - FB_HL) * 512 + t;
    if (i < 81920) {
      uint32_t o0, o1;
      tf_block(k1a, k1b, 0u, (uint32_t)i, o0, o1);
      uint32_t bits = o0 ^ o1;
      u1[i] = __uint_as_float((bits >> 9) | 0x3f800000u) - 1.0f;
    }
    return;
  }
  if (bid < FB_U2) {         // u2 uniforms
    int i = (bid - FB_U1) * 512 + t;
    if (i < 520192) {
      uint32_t o0, o1;
      tf_block(k2a, k2b, 0u, (uint32_t)i, o0, o1);
      uint32_t bits = o0 ^ o1;
      u2[i] = __uint_as_float((bits >> 9) | 0x3f800000u) - 1.0f;
    }
    return;
  }
  if (bid < FB_W1) {         // Wdst1 = Wdst@Wa1 (op-for-op as k_gemm32)
    int id = (bid - FB_U2) * 512 + t;
    int r = id >> 7, c = id & (CC - 1);
    float acc = 0.f;
#pragma unroll 8
    for (int k = 0; k < CC; k++) acc = __fmaf_rn(Wdst[r * CC + k], Wa1[k * CC + c], acc);
    Wdst1[id] = acc;
    return;
  }
  if (bid < FB_W2) {         // Wsrc1 = Wsrc@Wa1
    int id = (bid - FB_W1) * 512 + t;
    int r = id >> 7, c = id & (CC - 1);
    float acc = 0.f;
#pragma unroll 8
    for (int k = 0; k < CC; k++) acc = __fmaf_rn(Wsrc[r * CC + k], Wa1[k * CC + c], acc);
    Wsrc1[id] = acc;
    return;
  }
  if (bid == FB_WP) {        // Wp1 = Wp@Wa1 (3x128)
    if (t < 3 * CC) {
      int r = t >> 7, c = t & (CC - 1);
      float acc = 0.f;
#pragma unroll 8
      for (int k = 0; k < CC; k++) acc = __fmaf_rn(Wp[r * CC + k], Wa1[k * CC + c], acc);
      Wp1[t] = acc;
    }
    return;
  }
  // bid == FB_BP: bp1 = bp@Wa1 + ba1
  if (t < CC) {
    float acc = 0.f;
    for (int k = 0; k < CC; k++) acc = __fmaf_rn(bp[k], Wa1[k * CC + t], acc);
    bp1[t] = __fadd_rn(acc, ba1[t]);
  }
}

// ---------------- gather x1/pos1 + exact fp64 squared norms ----------------
__global__ __launch_bounds__(128) void k_gather(const float* __restrict__ pooled, const float* __restrict__ pos,
                                                const int* __restrict__ idxi, float* __restrict__ x1,
                                                float* __restrict__ x1T, float* __restrict__ pos1,
                                                double* __restrict__ sqp, double* __restrict__ sqf) {
  int m = blockIdx.x, t = threadIdx.x;
  int src = idxi[m];
  float v = pooled[(size_t)src * CC + t];
  x1[m * CC + t] = v;
  x1T[t * MM + m] = v;
  __shared__ double s2[CC];
  s2[t] = (double)v * (double)v;
  __syncthreads();
  if (t == 0) {
    double acc = 0.0;
    for (int i = 0; i < CC; i++) acc += s2[i];
    sqf[m] = acc;
    float X = pos[3 * src], Y = pos[3 * src + 1], Z = pos[3 * src + 2];
    pos1[3 * m] = X; pos1[3 * m + 1] = Y; pos1[3 * m + 2] = Z;
    sqp[m] = (double)X * X + (double)Y * Y + (double)Z * Z;
  }
}

// ---------------- pos kNN (k=16): DPP u64-min selection (same comparator: min d, tie min j) ----------------
__global__ __launch_bounds__(128) void k_knn_pos(const float* __restrict__ pos1, const double* __restrict__ sqp,
                                                 int* __restrict__ sedge) {
  int i = blockIdx.x, t = threadIdx.x;
  __shared__ float d[MM];
  __shared__ __align__(16) unsigned long long rr[2][2];
  double xi = pos1[3 * i], yi = pos1[3 * i + 1], zi = pos1[3 * i + 2], si = sqp[i];
  for (int j = t; j < MM; j += 128) {
    double dot = xi * (double)pos1[3 * j] + yi * (double)pos1[3 * j + 1] + zi * (double)pos1[3 * j + 2];
    float dd = (float)(si + sqp[j] - 2.0 * dot);
    d[j] = (j == i) ? __int_as_float(0x7f800000) : dd;
  }
  __syncthreads();
  int lane = t & 63, w = t >> 6;
  for (int s = 0; s < KPOS; s++) {
    unsigned long long best = ~0ull;
    for (int j = t; j < MM; j += 128) {
      uint32_t fb = __float_as_uint(d[j]);
      fb = (fb & 0x80000000u) ? ~fb : (fb | 0x80000000u);   // order-preserving flip
      unsigned long long key = ((unsigned long long)fb << 13) | (unsigned long long)(unsigned)j;
      if (key < best) best = key;
    }
    uint32_t klo = (uint32_t)best, khi = (uint32_t)(best >> 32);
    KNN_DPP_MIN_STEP(0x111)
    KNN_DPP_MIN_STEP(0x112)
    KNN_DPP_MIN_STEP(0x114)
    KNN_DPP_MIN_STEP(0x118)
    KNN_DPP_MIN_STEP(0x142)
    KNN_DPP_MIN_STEP(0x143)
    uint32_t wlo = (uint32_t)__builtin_amdgcn_readlane((int)klo, 63);
    uint32_t whi = (uint32_t)__builtin_amdgcn_readlane((int)khi, 63);
    unsigned long long wk = ((unsigned long long)whi << 32) | wlo;
    int p = s & 1;
    if (lane == 0) rr[p][w] = wk;
    __syncthreads();
    unsigned long long g = rr[p][0] < rr[p][1] ? rr[p][0] : rr[p][1];
    int bi = (int)(g & 8191ull);
    if (t == 0) sedge[EG + i * KPOS + s] = bi;
    if (t == (bi & 127)) d[bi] = __int_as_float(0x7f800000);
    __syncthreads();
  }
}

// ---------------- feature distance matrix: fp64 acc, split accumulators, clean LDS ----------------
__global__ __launch_bounds__(256) void k_dmat(const float* __restrict__ x1, const float* __restrict__ x1T,
                                              const double* __restrict__ sqf, float* __restrict__ D) {
  __shared__ float As2[16][128];   // [q][k]
  int bid = blockIdx.x;
  int i0 = (bid >> 4) << 4;
  int j0 = (bid & 15) << 8;
  int t = threadIdx.x;
  for (int u = t; u < 16 * CC; u += 256) {
    int q = u >> 7, k = u & (CC - 1);
    As2[q][k] = x1[(i0 + q) * CC + k];
  }
  __syncthreads();
  int j = j0 + t;
  double sj = sqf[j];
#pragma unroll
  for (int pass = 0; pass < 2; pass++) {
    double acc[8];
#pragma unroll
    for (int q = 0; q < 8; q++) acc[q] = 0.0;
    for (int k = 0; k < CC; k++) {
      double bv = (double)x1T[k * MM + j];
#pragma unroll
      for (int q = 0; q < 8; q++) acc[q] += (double)As2[pass * 8 + q][k] * bv;
    }
#pragma unroll
    for (int q = 0; q < 8; q++) {
      int i = i0 + pass * 8 + q;
      float d = (float)(sqf[i] + sj - 2.0 * acc[q]);
      D[(size_t)i * MM + j] = (i == j) ? __int_as_float(0x7f800000) : d;
    }
  }
}

// ---------------- top-127 selection per row ----------------
__global__ __launch_bounds__(256) void k_knn_feat(const float* __restrict__ D, int* __restrict__ nnf) {
  int tt = threadIdx.x;
  int lane = tt & 63, wid = tt >> 6;
  int i = blockIdx.x * 4 + wid;
  const float* drow = D + (size_t)i * MM;
  __shared__ float Lv[8][256];
  __shared__ int Lj[8][256];
  float lv[8]; int lj[8];
#pragma unroll
  for (int q = 0; q < 8; q++) { lv[q] = __int_as_float(0x7f800000); lj[q] = MM; }
  for (int tix = 0; tix < MM / 64; tix++) {
    int j = lane + (tix << 6);
    float v = drow[j];
    if (v < lv[7] || (v == lv[7] && j < lj[7])) {
      lv[7] = v; lj[7] = j;
#pragma unroll
      for (int q = 7; q >= 1; q--) {
        bool sw = (lv[q] < lv[q - 1]) || (lv[q] == lv[q - 1] && lj[q] < lj[q - 1]);
        if (sw) { float tv = lv[q]; lv[q] = lv[q - 1]; lv[q - 1] = tv;
                  int tj = lj[q]; lj[q] = lj[q - 1]; lj[q - 1] = tj; }
      }
    }
  }
#pragma unroll
  for (int q = 0; q < 8; q++) { Lv[q][tt] = lv[q]; Lj[q][tt] = lj[q]; }
  int hp = 0;
  for (int s = 0; s < KLARGE; s++) {
    float hv = (hp < 8) ? Lv[hp][tt] : __int_as_float(0x7f800000);
    int hj = (hp < 8) ? Lj[hp][tt] : MM;
    float bv = hv; int bj = hj;
#pragma unroll
    for (int off = 1; off < 64; off <<= 1) {
      float ov = __shfl_xor(bv, off);
      int oj = __shfl_xor(bj, off);
      if (ov < bv || (ov == bv && oj < bj)) { bv = ov; bj = oj; }
    }
    if (lane == 0) nnf[(size_t)i * KLARGE + s] = bj;
    if (bj < MM && (bj & 63) == lane) {
      hp++;
      if (hp == 8) {
        float nv[8]; int nj[8];
#pragma unroll
        for (int q = 0; q < 8; q++) { nv[q] = __int_as_float(0x7f800000); nj[q] = MM; }
        for (int tix = 0; tix < MM / 64; tix++) {
          int j = lane + (tix << 6);
          float v = drow[j];
          bool after = (v > bv) || (v == bv && j > bj);
          if (after && (v < nv[7] || (v == nv[7] && j < nj[7]))) {
            nv[7] = v; nj[7] = j;
#pragma unroll
            for (int q = 7; q >= 1; q--) {
              bool sw = (nv[q] < nv[q - 1]) || (nv[q] == nv[q - 1] && nj[q] < nj[q - 1]);
              if (sw) { float tv = nv[q]; nv[q] = nv[q - 1]; nv[q - 1] = tv;
                        int tj = nj[q]; nj[q] = nj[q - 1]; nj[q - 1] = tj; }
            }
          }
        }
#pragma unroll
        for (int q = 0; q < 8; q++) { Lv[q][tt] = nv[q]; Lj[q][tt] = nj[q]; }
        hp = 0;
      }
    }
  }
}

// ---------------- emb ----------------
__global__ __launch_bounds__(64) void k_emb(const float* __restrict__ hg, const float* __restrict__ Wg2,
                                            const float* __restrict__ bg2, const float* __restrict__ u1,
                                            float* __restrict__ emb) {
  int m = blockIdx.x, t = threadIdx.x;
  if (t >= 20) return;
  double acc = 0.0;
  for (int k = 0; k < CC; k++) acc += (double)hg[m * CC + k] * (double)Wg2[k * 20 + t];
  float v = (float)acc;
  v = __fadd_rn(v, bg2[t]);
  v = __fadd_rn(v, __fmul_rn(u1[m * 20 + t], 1e-4f));
  emb[m * 20 + t] = v;
}

// ---------------- gumbel top-16 ----------------
__global__ __launch_bounds__(128) void k_gumbel(const float* __restrict__ emb, const int* __restrict__ nnf,
                                                const float* __restrict__ u2, int* __restrict__ sedge) {
  int i = blockIdx.x, t = threadIdx.x;
  __shared__ float ei[20];
  __shared__ float sc[KLARGE];
  __shared__ int sj[KLARGE];
  if (t < 20) ei[t] = emb[i * 20 + t];
  __syncthreads();
  if (t < KLARGE) {
    int j = nnf[(size_t)i * KLARGE + t];
    double res = 0.0;
#pragma unroll
    for (int q = 0; q < 20; q++) {
      float df = __fsub_rn(ei[q], emb[j * 20 + q]);
      res += (double)df * (double)df;
    }
    float dist = (float)sqrt(res);
    float d2 = __fmul_rn(dist, dist);
    float p = expf(-d2);
    float u = u2[i * KLARGE + t];
    float inner = logf(__fadd_rn(u, 1e-20f));
    float g = -logf(__fadd_rn(-inner, 1e-20f));
    sc[t] = __fadd_rn(logf(__fadd_rn(p, 1e-20f)), g);
    sj[t] = j;
  }
  __syncthreads();
  if (t == 0) {
    for (int s = 0; s < KDOWN; s++) {
      float bv = -__int_as_float(0x7f800000); int bs = 0;
      for (int q = 0; q < KLARGE; q++)
        if (sc[q] > bv) { bv = sc[q]; bs = q; }
      sedge[i * KDOWN + s] = sj[bs];
      sc[bs] = -__int_as_float(0x7f800000);
    }
  }
}

// ---------------- alpha1 (folded) ----------------
__global__ __launch_bounds__(256) void k_alpha1_elw(const float* __restrict__ P, const float* __restrict__ Q,
                                                    const float* __restrict__ pos1, const int* __restrict__ sedge,
                                                    const float* __restrict__ Wp1, const float* __restrict__ bp1,
                                                    float* __restrict__ alpha) {
  int id = blockIdx.x * 256 + threadIdx.x;
  int e = id >> 7, t = id & (CC - 1);
  int tgt = (e < EG) ? (e >> 4) : ((e - EG) >> 4);
  int src = sedge[e];
  float dpx = __fsub_rn(pos1[3 * tgt], pos1[3 * src]);
  float dpy = __fsub_rn(pos1[3 * tgt + 1], pos1[3 * src + 1]);
  float dpz = __fsub_rn(pos1[3 * tgt + 2], pos1[3 * src + 2]);
  float v = P[(size_t)tgt * CC + t] - Q[(size_t)src * CC + t];
  v = __fmaf_rn(dpx, Wp1[t], v);
  v = __fmaf_rn(dpy, Wp1[CC + t], v);
  v = __fmaf_rn(dpz, Wp1[2 * CC + t], v);
  alpha[(size_t)id] = __fadd_rn(v, bp1[t]);
}

// ---------------- alpha2: tiled fp32 GEMM with fused BN+ReLU staging ----------------
__global__ __launch_bounds__(256) void k_alpha2_gemm(const float* __restrict__ alpha_in,
                                                     float* __restrict__ alpha_out,
                                                     const float* __restrict__ mean, const float* __restrict__ var,
                                                     const float* __restrict__ g, const float* __restrict__ b,
                                                     const float* __restrict__ Wa2, const float* __restrict__ ba2) {
  __shared__ float As[16][132];
  __shared__ float Bs[16][132];
  __shared__ float scl[CC], shf[CC];
  int t = threadIdx.x;
  int e0 = blockIdx.x * 128;
  if (t < CC) {
    float sd = __fsqrt_rn(__fadd_rn(var[t], 1e-5f));
    float s = __fdiv_rn(g[t], sd);
    scl[t] = s;
    shf[t] = __fsub_rn(b[t], __fmul_rn(mean[t], s));
  }
  int te = t >> 4, tc = t & 15;
  float acc[8][8];
#pragma unroll
  for (int ii = 0; ii < 8; ii++)
#pragma unroll
    for (int jj = 0; jj < 8; jj++) acc[ii][jj] = 0.f;
  for (int kc = 0; kc < CC; kc += 16) {
    __syncthreads();
    for (int u = t; u < 16 * 128; u += 256) {
      int ee = u >> 4, kk = u & 15;
      float a = alpha_in[(size_t)(e0 + ee) * CC + kc + kk];
      int k = kc + kk;
      As[kk][ee] = fmaxf(__fmaf_rn(a, scl[k], shf[k]), 0.f);
    }
    for (int u = t; u < 16 * 128; u += 256) {
      int kk = u >> 7, c = u & 127;
      Bs[kk][c] = Wa2[(kc + kk) * CC + c];
    }
    __syncthreads();
#pragma unroll
    for (int kk = 0; kk < 16; kk++) {
      float av[8], bv[8];
      *(float4*)&av[0] = *(const float4*)&As[kk][te * 8];
      *(float4*)&av[4] = *(const float4*)&As[kk][te * 8 + 4];
      *(float4*)&bv[0] = *(const float4*)&Bs[kk][tc * 8];
      *(float4*)&bv[4] = *(const float4*)&Bs[kk][tc * 8 + 4];
#pragma unroll
      for (int ii = 0; ii < 8; ii++)
#pragma unroll
        for (int jj = 0; jj < 8; jj++) acc[ii][jj] = __fmaf_rn(av[ii], bv[jj], acc[ii][jj]);
    }
  }
#pragma unroll
  for (int ii = 0; ii < 8; ii++) {
    int e = e0 + te * 8 + ii;
#pragma unroll
    for (int jj = 0; jj < 8; jj++) {
      int c = tc * 8 + jj;
      alpha_out[(size_t)e * CC + c] = __fadd_rn(acc[ii][jj], ba2[c]);
    }
  }
}

// ---------------- per-target softmax attention + aggregate ----------------
__global__ __launch_bounds__(128) void k_outagg(const float* __restrict__ alpha, const float* __restrict__ vmat,
                                                const float* __restrict__ pos1, const int* __restrict__ sedge,
                                                const float* __restrict__ Wp, const float* __restrict__ bp,
                                                float* __restrict__ outb) {
  int m = blockIdx.x, t = threadIdx.x;
  float al[32], dl[32]; int sr[32];
  float amax = -__int_as_float(0x7f800000);
  float pmx = pos1[3 * m], pmy = pos1[3 * m + 1], pmz = pos1[3 * m + 2];
  float wp0 = Wp[t], wp1 = Wp[CC + t], wp2 = Wp[2 * CC + t], bpt = bp[t];
#pragma unroll
  for (int e = 0; e < 32; e++) {
    int row = (e < 16) ? (m * 16 + e) : (EG + m * 16 + (e - 16));
    int src = sedge[row];
    sr[e] = src;
    float a = alpha[(size_t)row * CC + t];
    al[e] = a;
    amax = fmaxf(amax, a);
    float d0 = __fsub_rn(pmx, pos1[3 * src]);
    float d1 = __fsub_rn(pmy, pos1[3 * src + 1]);
    float d2 = __fsub_rn(pmz, pos1[3 * src + 2]);
    float del = __fmaf_rn(d2, wp2, __fmaf_rn(d1, wp1, __fmul_rn(d0, wp0)));
    dl[e] = __fadd_rn(del, bpt);
  }
  float s1 = 0.f, s2 = 0.f;
#pragma unroll
  for (int e = 0; e < 32; e++) {
    float ea = expf(__fsub_rn(al[e], amax));
    s1 = __fadd_rn(s1, ea);
    float val = __fadd_rn(vmat[sr[e] * CC + t], dl[e]);
    s2 = __fmaf_rn(ea, val, s2);
  }
  outb[m * CC + t] = __fdiv_rn(s2, __fadd_rn(s1, 1e-16f));
}

// =====================================================================
extern "C" void kernel_launch(void* const* d_in, const int* in_sizes, int n_in,
                              void* d_out, int out_size, void* d_ws, size_t ws_size,
                              hipStream_t stream) {
  (void)in_sizes; (void)n_in; (void)out_size; (void)ws_size;
  const float* x    = (const float*)d_in[0];
  const float* pos  = (const float*)d_in[1];
  const int*   ei   = (const int*)d_in[2];
  const float* Wd   = (const float*)d_in[3];
  const float* bd   = (const float*)d_in[4];
  const float* gd   = (const float*)d_in[5];
  const float* btd  = (const float*)d_in[6];
  const float* Wg1  = (const float*)d_in[7];
  const float* bg1  = (const float*)d_in[8];
  const float* gg   = (const float*)d_in[9];
  const float* btg  = (const float*)d_in[10];
  const float* Wg2  = (const float*)d_in[11];
  const float* bg2  = (const float*)d_in[12];
  const float* Wlin = (const float*)d_in[13];
  const float* Wsrc = (const float*)d_in[14];
  const float* Wdst = (const float*)d_in[15];
  const float* Wp   = (const float*)d_in[16];
  const float* bp   = (const float*)d_in[17];
  const float* Wa1  = (const float*)d_in[18];
  const float* ba1  = (const float*)d_in[19];
  const float* ga   = (const float*)d_in[20];
  const float* bta  = (const float*)d_in[21];
  const float* Wa2  = (const float*)d_in[22];
  const float* ba2  = (const float*)d_in[23];
  const float* Wu   = (const float*)d_in[24];
  const float* bu   = (const float*)d_in[25];
  float* out = (float*)d_out;

  char* ws = (char*)d_ws;
  double* dsum = (double*)(ws + 0);
  double* dsq  = (double*)(ws + 1024);
  float* fmean = (float*)(ws + 2048);
  float* fvar  = (float*)(ws + 2560);
  float* BIG   = (float*)(ws + 4096);      // 64MB: D matrix, then alpha1/alpha2
  size_t off = 4096 + (size_t)16777216 * 4;
  auto alloc = [&](size_t nbytes) { void* p = ws + off; off += (nbytes + 255) & ~(size_t)255; return p; };
  float* h_lin  = (float*)alloc((size_t)NNODE * CC * 4);
  float* h      = (float*)alloc((size_t)NNODE * CC * 4);
  float* pooled = (float*)alloc((size_t)NNODE * CC * 4);
  float* x1     = (float*)alloc((size_t)MM * CC * 4);
  float* x1T    = (float*)alloc((size_t)MM * CC * 4);
  float* hgl    = (float*)alloc((size_t)MM * CC * 4);
  float* hg     = (float*)alloc((size_t)MM * CC * 4);
  float* Pm     = (float*)alloc((size_t)MM * CC * 4);
  float* Qm     = (float*)alloc((size_t)MM * CC * 4);
  float* vmat   = (float*)alloc((size_t)MM * CC * 4);
  float* outb   = (float*)alloc((size_t)MM * CC * 4);
  float* pos1   = (float*)alloc((size_t)MM * 3 * 4);
  double* sqp   = (double*)alloc((size_t)MM * 8);
  double* sqf   = (double*)alloc((size_t)MM * 8);
  float* emb    = (float*)alloc((size_t)MM * 20 * 4);
  float* u1     = (float*)alloc(81920 * 4);
  float* u2     = (float*)alloc(520192 * 4);
  int* idxi     = (int*)alloc(MM * 4);
  int* nnf      = (int*)alloc((size_t)MM * KLARGE * 4);
  int* sedge    = (int*)alloc(ETOT * 4);
  double* partA = (double*)alloc(64 * CC * 8);
  double* partB = (double*)alloc(64 * CC * 8);
  float* Wdst1  = (float*)alloc(CC * CC * 4);
  float* Wsrc1  = (float*)alloc(CC * CC * 4);
  float* Wp1    = (float*)alloc(3 * CC * 4);
  float* bp1    = (float*)alloc(CC * 4);

  // threefry partitionable split: child j = outputs of tf(key,(0,j)); key(42)=(0,42)
  uint32_t o0, o1, k1a, k1b, k2a, k2b;
  tf_block(0u, 42u, 0u, 0u, o0, o1); k1a = o0; k1b = o1;
  tf_block(0u, 42u, 0u, 1u, o0, o1); k2a = o0; k2b = o1;

  // ---- front: FPS (block 0) + all input-only work on the other 255 CUs ----
  k_front<<<dim3(FB_GRID), dim3(512), 0, stream>>>(pos, idxi, x, Wd, bd, h_lin,
                                                   u1, u2, k1a, k1b, k2a, k2b,
                                                   Wdst, Wsrc, Wa1, Wp, bp, ba1,
                                                   Wdst1, Wsrc1, Wp1, bp1);

  // ---- downlayer (stats -> BN -> pool -> gather) ----
  k_colsum_part<<<dim3(64), dim3(128), 0, stream>>>(h_lin, NNODE, 128, partA);
  k_colmean<<<dim3(1), dim3(128), 0, stream>>>(partA, 64, (double)NNODE, fmean);
  k_colvar_part<<<dim3(64), dim3(128), 0, stream>>>(h_lin, NNODE, 128, fmean, partB);
  k_colvar_fin<<<dim3(1), dim3(128), 0, stream>>>(partB, 64, (double)NNODE, fvar);
  k_bnrelu<<<dim3(NNODE * CC / 256), dim3(256), 0, stream>>>(h_lin, fmean, fvar, gd, btd, h, pooled, NNODE * CC);
  k_pool<<<dim3(NEDGE * CC / 256), dim3(256), 0, stream>>>(h, ei, pooled);
  k_gather<<<dim3(MM), dim3(128), 0, stream>>>(pooled, pos, idxi, x1, x1T, pos1, sqp, sqf);

  // ---- generate_graph ----
  k_knn_pos<<<dim3(MM), dim3(128), 0, stream>>>(pos1, sqp, sedge);
  k_dmat<<<dim3(4096), dim3(256), 0, stream>>>(x1, x1T, sqf, BIG);
  k_knn_feat<<<dim3(MM / 4), dim3(256), 0, stream>>>(BIG, nnf);
  k_gemm64<CC><<<dim3(MM * CC / 256), dim3(256), 0, stream>>>(x1, Wg1, bg1, hgl, MM);
  k_colsum_part<<<dim3(32), dim3(128), 0, stream>>>(hgl, MM, 128, partA);
  k_colmean<<<dim3(1), dim3(128), 0, stream>>>(partA, 32, (double)MM, fmean);
  k_colvar_part<<<dim3(32), dim3(128), 0, stream>>>(hgl, MM, 128, fmean, partB);
  k_colvar_fin<<<dim3(1), dim3(128), 0, stream>>>(partB, 32, (double)MM, fvar);
  k_bnrelu<<<dim3(MM * CC / 256), dim3(256), 0, stream>>>(hgl, fmean, fvar, gg, btg, hg, (float*)nullptr, MM * CC);
  k_emb<<<dim3(MM), dim3(64), 0, stream>>>(hg, Wg2, bg2, u1, emb);
  k_gumbel<<<dim3(MM), dim3(128), 0, stream>>>(emb, nnf, u2, sedge);

  // ---- PointTransformerConv (folded alpha1 + tiled alpha2) ----
  k_gemm32<<<dim3(MM * CC / 256), dim3(256), 0, stream>>>(x1, Wdst1, (const float*)nullptr, Pm, MM);
  k_gemm32<<<dim3(MM * CC / 256), dim3(256), 0, stream>>>(x1, Wsrc1, (const float*)nullptr, Qm, MM);
  k_gemm32<<<dim3(MM * CC / 256), dim3(256), 0, stream>>>(x1, Wlin, (const float*)nullptr, vmat, MM);
  k_alpha1_elw<<<dim3(ETOT * CC / 256), dim3(256), 0, stream>>>(Pm, Qm, pos1, sedge, Wp1, bp1, BIG);
  hipMemsetAsync(ws, 0, 2048, stream);
  k_colstat64<<<dim3(256), dim3(128), 0, stream>>>(BIG, ETOT, 512, dsum, dsq);
  k_finstat<<<dim3(1), dim3(128), 0, stream>>>(dsum, dsq, (double)ETOT, fmean, fvar);
  k_alpha2_gemm<<<dim3(ETOT / 128), dim3(256), 0, stream>>>(BIG, BIG, fmean, fvar, ga, bta, Wa2, ba2);
  k_outagg<<<dim3(MM), dim3(128), 0, stream>>>(BIG, vmat, pos1, sedge, Wp, bp, outb);
  k_gemm_res<<<dim3(MM * CC / 256), dim3(256), 0, stream>>>(outb, Wu, bu, x1, out, MM);
}